// Round 1
// baseline (253.792 us; speedup 1.0000x reference)
//
#include <hip/hip_runtime.h>

#define BATCHN 131072
#define M_TILE 128
#define HPITCH 264            // 256 + 8 halves pad -> 528B rows, 16B aligned, 4-way max conflict
#define NET_STRIDE 73728      // halves per packed net: 4096 (w1p) + 65536 (w2p) + 4096 (w3p)
#define W2P_OFF 4096
#define W3P_OFF 69632
#define PACK_TOTAL (4 * NET_STRIDE)

typedef _Float16 half8 __attribute__((ext_vector_type(8)));
typedef float f32x16 __attribute__((ext_vector_type(16)));
typedef float f32x4  __attribute__((ext_vector_type(4)));

struct __align__(16) SMEM {
    _Float16 xin[M_TILE][16];       // stage input, K padded to 16 (cols 8..15 zero)
    _Float16 Ha[M_TILE][HPITCH];    // hidden ping
    _Float16 Hb[M_TILE][HPITCH];    // hidden pong
    float s_tile[M_TILE][8];
    float t_tile[M_TILE][8];
    float ldet[M_TILE];
};                                  // ~148 KB -> 1 block/CU

// ---------------- weight pre-pack: f32 -> f16, fragment-ordered ----------------
// w1p: 8 chunks (n-tile) x 512   lane l,j -> W1[nt*32+(l&31)][(l>>5)*8+j], k>=8 -> 0
// w2p: (nt*16+ks) chunks x 512   lane l,j -> W2[nt*32+(l&31)][ks*16+(l>>5)*8+j]
// w3p: 8 chunks (ks) x 512       lane l,j -> W3[l&15][ks*32+(l>>4)*8+j], n>=8 -> 0
__global__ __launch_bounds__(256) void pack_weights(
    const float* __restrict__ s1w1, const float* __restrict__ s1w2, const float* __restrict__ s1w3,
    const float* __restrict__ t1w1, const float* __restrict__ t1w2, const float* __restrict__ t1w3,
    const float* __restrict__ s2w1, const float* __restrict__ s2w2, const float* __restrict__ s2w3,
    const float* __restrict__ t2w1, const float* __restrict__ t2w2, const float* __restrict__ t2w3,
    _Float16* __restrict__ wp)
{
    int tid = blockIdx.x * 256 + threadIdx.x;
    if (tid >= PACK_TOTAL) return;
    int net = tid / NET_STRIDE;
    int rem = tid - net * NET_STRIDE;
    const float* w1 = (net == 0) ? s1w1 : (net == 1) ? t1w1 : (net == 2) ? s2w1 : t2w1;
    const float* w2 = (net == 0) ? s1w2 : (net == 1) ? t1w2 : (net == 2) ? s2w2 : t2w2;
    const float* w3 = (net == 0) ? s1w3 : (net == 1) ? t1w3 : (net == 2) ? s2w3 : t2w3;
    float val;
    if (rem < W2P_OFF) {
        int nt = rem >> 9;
        int l  = (rem >> 3) & 63;
        int j  = rem & 7;
        int n  = nt * 32 + (l & 31);
        int k  = ((l >> 5) << 3) + j;
        val = (k < 8) ? w1[n * 8 + k] : 0.0f;
    } else if (rem < W3P_OFF) {
        int r = rem - W2P_OFF;
        int chunk = r >> 9;
        int nt = chunk >> 4, ks = chunk & 15;
        int l = (r >> 3) & 63, j = r & 7;
        int n = nt * 32 + (l & 31);
        int k = ks * 16 + ((l >> 5) << 3) + j;
        val = w2[n * 256 + k];
    } else {
        int r = rem - W3P_OFF;
        int ks = r >> 9;
        int l = (r >> 3) & 63, j = r & 7;
        int n = l & 15;
        int k = ks * 32 + ((l >> 4) & 3) * 8 + j;
        val = (n < 8) ? w3[n * 256 + k] : 0.0f;
    }
    wp[tid] = (_Float16)val;
}

// ---------------- fused MLP: xin -> Ha -> Hb -> stile ----------------
template <bool IS_S>
__device__ __forceinline__ void mlp_forward(
    const _Float16* __restrict__ wp,
    const float* __restrict__ b1, const float* __restrict__ b2, const float* __restrict__ b3,
    SMEM& sm, float (*__restrict__ stile)[8])
{
    const int tid  = threadIdx.x;
    const int wave = tid >> 6, lane = tid & 63;
    const int l31  = lane & 31, hi = lane >> 5;
    const int rg   = wave >> 1, cg = wave & 1;   // 4 row-groups x 2 col-groups

    // ---- layer 1: xin(128x16) @ W1p^T -> Ha(128x256), relu
    {
        half8 a = *(const half8*)&sm.xin[rg * 32 + l31][hi * 8];
        f32x16 acc[4];
        #pragma unroll
        for (int ct = 0; ct < 4; ++ct) {
            const int nt = cg * 4 + ct;
            half8 b = *(const half8*)&wp[nt * 512 + lane * 8];
            f32x16 z = {};
            acc[ct] = __builtin_amdgcn_mfma_f32_32x32x16_f16(a, b, z, 0, 0, 0);
        }
        #pragma unroll
        for (int ct = 0; ct < 4; ++ct) {
            const int n = cg * 128 + ct * 32 + l31;
            const float bias = b1[n];
            #pragma unroll
            for (int r = 0; r < 16; ++r) {
                const int row = rg * 32 + (r & 3) + 8 * (r >> 2) + 4 * hi;  // verified C/D map
                float v = acc[ct][r] + bias;
                sm.Ha[row][n] = (_Float16)fmaxf(v, 0.0f);
            }
        }
    }
    __syncthreads();

    // ---- layer 2: Ha(128x256) @ W2p^T -> Hb(128x256), relu
    {
        const _Float16* __restrict__ w2p = wp + W2P_OFF;
        const int arow = rg * 32 + l31;
        f32x16 acc[4] = {};
        #pragma unroll 4
        for (int ks = 0; ks < 16; ++ks) {
            half8 a = *(const half8*)&sm.Ha[arow][ks * 16 + hi * 8];
            #pragma unroll
            for (int ct = 0; ct < 4; ++ct) {
                const int nt = cg * 4 + ct;
                half8 b = *(const half8*)&w2p[(nt * 16 + ks) * 512 + lane * 8];
                acc[ct] = __builtin_amdgcn_mfma_f32_32x32x16_f16(a, b, acc[ct], 0, 0, 0);
            }
        }
        #pragma unroll
        for (int ct = 0; ct < 4; ++ct) {
            const int n = cg * 128 + ct * 32 + l31;
            const float bias = b2[n];
            #pragma unroll
            for (int r = 0; r < 16; ++r) {
                const int row = rg * 32 + (r & 3) + 8 * (r >> 2) + 4 * hi;
                float v = acc[ct][r] + bias;
                sm.Hb[row][n] = (_Float16)fmaxf(v, 0.0f);
            }
        }
    }
    __syncthreads();

    // ---- layer 3: Hb(128x256) @ W3p^T -> 128x16 (8 valid), 16x16x32 shape
    {
        const _Float16* __restrict__ w3p = wp + W3P_OFF;
        const int l15 = lane & 15, q = lane >> 4;
        f32x4 acc = {};
        #pragma unroll
        for (int ks = 0; ks < 8; ++ks) {
            half8 a = *(const half8*)&sm.Hb[wave * 16 + l15][ks * 32 + q * 8];
            half8 b = *(const half8*)&w3p[ks * 512 + lane * 8];
            acc = __builtin_amdgcn_mfma_f32_16x16x32_f16(a, b, acc, 0, 0, 0);
        }
        if (l15 < 8) {
            const float bias = b3[l15];
            #pragma unroll
            for (int r = 0; r < 4; ++r) {
                const int row = wave * 16 + q * 4 + r;   // verified 16x16 C/D map
                float v = acc[r] + bias;
                stile[row][l15] = IS_S ? tanhf(v) : v;
            }
        }
    }
    // trailing barrier not needed: next writer of Ha/Hb is past its own barrier
    // before touching anything this layer still reads (see barrier analysis).
}

__global__ __launch_bounds__(512) void coupling_kernel(
    const float* __restrict__ x, const _Float16* __restrict__ wp,
    const float* __restrict__ s1b1, const float* __restrict__ s1b2, const float* __restrict__ s1b3,
    const float* __restrict__ t1b1, const float* __restrict__ t1b2, const float* __restrict__ t1b3,
    const float* __restrict__ s2b1, const float* __restrict__ s2b2, const float* __restrict__ s2b3,
    const float* __restrict__ t2b1, const float* __restrict__ t2b2, const float* __restrict__ t2b3,
    float* __restrict__ out)
{
    __shared__ SMEM sm;
    const int tid = threadIdx.x;
    const long row0 = (long)blockIdx.x * M_TILE;

    // stage A input: x2 -> xin (cols 0..7), zero pad (cols 8..15)
    for (int e = tid; e < M_TILE * 16; e += 512) {
        int row = e >> 4, c = e & 15;
        float v = (c < 8) ? x[(row0 + row) * 16 + 8 + c] : 0.0f;
        sm.xin[row][c] = (_Float16)v;
    }
    __syncthreads();

    mlp_forward<true >(wp + 0 * NET_STRIDE, s1b1, s1b2, s1b3, sm, sm.s_tile);  // s2 = tanh(.)
    mlp_forward<false>(wp + 1 * NET_STRIDE, t1b1, t1b2, t1b3, sm, sm.t_tile);  // t2
    __syncthreads();

    // y1 = x1 * exp(s2) + t2 ; ldet partial ; xin <- y1
    for (int e = tid; e < M_TILE * 8; e += 512) {
        int row = e >> 3, c = e & 7;
        float s = sm.s_tile[row][c];
        float t = sm.t_tile[row][c];
        float x1 = x[(row0 + row) * 16 + c];
        float y = x1 * expf(s) + t;
        out[(row0 + row) * 16 + c] = y;
        sm.xin[row][c] = (_Float16)y;   // cols 8..15 remain zero
    }
    if (tid < M_TILE) {
        float acc = 0.0f;
        #pragma unroll
        for (int c = 0; c < 8; ++c) acc += sm.s_tile[tid][c];
        sm.ldet[tid] = acc;
    }
    __syncthreads();

    mlp_forward<true >(wp + 2 * NET_STRIDE, s2b1, s2b2, s2b3, sm, sm.s_tile);  // s1 = tanh(.)
    mlp_forward<false>(wp + 3 * NET_STRIDE, t2b1, t2b2, t2b3, sm, sm.t_tile);  // t1
    __syncthreads();

    // y2 = x2 * exp(s1) + t1 ; log_det
    for (int e = tid; e < M_TILE * 8; e += 512) {
        int row = e >> 3, c = e & 7;
        float s = sm.s_tile[row][c];
        float t = sm.t_tile[row][c];
        float x2 = x[(row0 + row) * 16 + 8 + c];
        out[(row0 + row) * 16 + 8 + c] = x2 * expf(s) + t;
    }
    if (tid < M_TILE) {
        float acc = sm.ldet[tid];
        #pragma unroll
        for (int c = 0; c < 8; ++c) acc += sm.s_tile[tid][c];
        out[(long)BATCHN * 16 + row0 + tid] = acc;
    }
}

extern "C" void kernel_launch(void* const* d_in, const int* in_sizes, int n_in,
                              void* d_out, int out_size, void* d_ws, size_t ws_size,
                              hipStream_t stream)
{
    const float* x = (const float*)d_in[0];
    // inputs: x, then per net (s1,t1,s2,t2): w1,b1,w2,b2,w3,b3
    const float* s1w1 = (const float*)d_in[1];  const float* s1b1 = (const float*)d_in[2];
    const float* s1w2 = (const float*)d_in[3];  const float* s1b2 = (const float*)d_in[4];
    const float* s1w3 = (const float*)d_in[5];  const float* s1b3 = (const float*)d_in[6];
    const float* t1w1 = (const float*)d_in[7];  const float* t1b1 = (const float*)d_in[8];
    const float* t1w2 = (const float*)d_in[9];  const float* t1b2 = (const float*)d_in[10];
    const float* t1w3 = (const float*)d_in[11]; const float* t1b3 = (const float*)d_in[12];
    const float* s2w1 = (const float*)d_in[13]; const float* s2b1 = (const float*)d_in[14];
    const float* s2w2 = (const float*)d_in[15]; const float* s2b2 = (const float*)d_in[16];
    const float* s2w3 = (const float*)d_in[17]; const float* s2b3 = (const float*)d_in[18];
    const float* t2w1 = (const float*)d_in[19]; const float* t2b1 = (const float*)d_in[20];
    const float* t2w2 = (const float*)d_in[21]; const float* t2b2 = (const float*)d_in[22];
    const float* t2w3 = (const float*)d_in[23]; const float* t2b3 = (const float*)d_in[24];

    _Float16* wp = (_Float16*)d_ws;   // 589824 B used; repacked every launch (ws is re-poisoned)

    pack_weights<<<PACK_TOTAL / 256, 256, 0, stream>>>(
        s1w1, s1w2, s1w3, t1w1, t1w2, t1w3, s2w1, s2w2, s2w3, t2w1, t2w2, t2w3, wp);

    coupling_kernel<<<BATCHN / M_TILE, 512, 0, stream>>>(
        x, wp,
        s1b1, s1b2, s1b3, t1b1, t1b2, t1b3,
        s2b1, s2b2, s2b3, t2b1, t2b2, t2b3,
        (float*)d_out);
}

// Round 3
// 204.947 us; speedup vs baseline: 1.2383x; 1.2383x over previous
//
#include <hip/hip_runtime.h>

#define BATCHN 131072
#define M_TILE 64
#define HPITCH 264            // halves per H row = 528B (16B-aligned rows, bias chunk at col 256)
#define W2P_OFF 4096          // halves: w1p = 8 chunks x 512
#define W3P_OFF 73728         // w2p = 8*17 chunks x 512
#define NET_STRIDE 77824      // + w3p = 8 chunks x 512
#define PACK_TOTAL (4 * NET_STRIDE)

typedef _Float16 hv8 __attribute__((ext_vector_type(8)));
typedef _Float16 hv4 __attribute__((ext_vector_type(4)));
typedef __fp16  fp16x2 __attribute__((ext_vector_type(2)));
typedef float f32x16 __attribute__((ext_vector_type(16)));
typedef float f32x4  __attribute__((ext_vector_type(4)));

struct __align__(16) SMEM {
    _Float16 xin[M_TILE][16];     // K=16: cols0..7 = input, col8 = 1.0 (bias), rest 0
    _Float16 Ha[M_TILE][HPITCH];  // H layout: [m][n], XOR-swizzled 16B chunks; col256=1.0,257..263=0
    _Float16 Hb[M_TILE][HPITCH];
    float s_tile[M_TILE][8];
    float t_tile[M_TILE][8];
    float ldet[M_TILE];
};                                // 73984 B -> 2 blocks/CU

// ---------------- weight pre-pack: f32 -> f16, A-fragment order, biases folded ----------------
// w1p: 8 chunks x 512:  lane l,j -> n = nt*32+(l&31), k=(l>>5)*8+j: k<8 -> W1[n][k]; k==8 -> b1[n]; else 0
// w2p: (nt*17+ks) x 512: ks<16 -> W2[n][ks*16+(l>>5)*8+j]; ks==16: slot0 -> b2[n], else 0
// w3p: 8 chunks x 512:  n=l&15 (<8 valid), k=ks*32+(l>>4)*8+j -> W3[n][k]
__global__ __launch_bounds__(256) void pack_weights(
    const float* __restrict__ s1w1, const float* __restrict__ s1b1, const float* __restrict__ s1w2, const float* __restrict__ s1b2, const float* __restrict__ s1w3,
    const float* __restrict__ t1w1, const float* __restrict__ t1b1, const float* __restrict__ t1w2, const float* __restrict__ t1b2, const float* __restrict__ t1w3,
    const float* __restrict__ s2w1, const float* __restrict__ s2b1, const float* __restrict__ s2w2, const float* __restrict__ s2b2, const float* __restrict__ s2w3,
    const float* __restrict__ t2w1, const float* __restrict__ t2b1, const float* __restrict__ t2w2, const float* __restrict__ t2b2, const float* __restrict__ t2w3,
    _Float16* __restrict__ wp)
{
    int tid = blockIdx.x * 256 + threadIdx.x;
    if (tid >= PACK_TOTAL) return;
    int net = tid / NET_STRIDE;
    int rem = tid - net * NET_STRIDE;
    const float* w1 = (net == 0) ? s1w1 : (net == 1) ? t1w1 : (net == 2) ? s2w1 : t2w1;
    const float* b1 = (net == 0) ? s1b1 : (net == 1) ? t1b1 : (net == 2) ? s2b1 : t2b1;
    const float* w2 = (net == 0) ? s1w2 : (net == 1) ? t1w2 : (net == 2) ? s2w2 : t2w2;
    const float* b2 = (net == 0) ? s1b2 : (net == 1) ? t1b2 : (net == 2) ? s2b2 : t2b2;
    const float* w3 = (net == 0) ? s1w3 : (net == 1) ? t1w3 : (net == 2) ? s2w3 : t2w3;
    float val;
    if (rem < W2P_OFF) {
        int nt = rem >> 9;
        int l  = (rem >> 3) & 63, j = rem & 7;
        int n  = nt * 32 + (l & 31);
        int k  = ((l >> 5) << 3) + j;
        val = (k < 8) ? w1[n * 8 + k] : (k == 8 ? b1[n] : 0.0f);
    } else if (rem < W3P_OFF) {
        int r = rem - W2P_OFF;
        int chunk = r >> 9;
        int nt = chunk / 17, ks = chunk - nt * 17;
        int l = (r >> 3) & 63, j = r & 7;
        int n = nt * 32 + (l & 31);
        int kk = ((l >> 5) << 3) + j;
        val = (ks < 16) ? w2[n * 256 + ks * 16 + kk] : (kk == 0 ? b2[n] : 0.0f);
    } else {
        int r = rem - W3P_OFF;
        int ks = r >> 9;
        int l = (r >> 3) & 63, j = r & 7;
        int n = l & 15;
        int k = ks * 32 + ((l >> 4) & 3) * 8 + j;
        val = (n < 8) ? w3[n * 256 + k] : 0.0f;
    }
    wp[tid] = (_Float16)val;
}

#define MFMA32(A,B,C) __builtin_amdgcn_mfma_f32_32x32x16_f16((A),(B),(C),0,0,0)

// epilogue helper: relu+pack 4 consecutive-n values, b64 write with XOR swizzle
__device__ __forceinline__ void epi_write(_Float16* __restrict__ H, int m, int g, int nt, int q, int hi,
                                          float v0, float v1, float v2, float v3)
{
    union { hv4 h4; fp16x2 h2[2]; } u;
    u.h2[0] = __builtin_amdgcn_cvt_pkrtz(fmaxf(v0, 0.f), fmaxf(v1, 0.f));
    u.h2[1] = __builtin_amdgcn_cvt_pkrtz(fmaxf(v2, 0.f), fmaxf(v3, 0.f));
    int c = 4 * nt + q;
    *(hv4*)(H + m * HPITCH + (((c ^ g) << 3) + 4 * hi)) = u.h4;
}

// ---------------- fused MLP: xin -> Ha -> Hb -> stile (D = W * X^T form) ----------------
template <bool IS_S>
__device__ __forceinline__ void mlp_forward(
    const _Float16* __restrict__ wp, const float* __restrict__ b3,
    SMEM& sm, float (*__restrict__ stile)[8])
{
    const int tid  = threadIdx.x;
    const int wave = tid >> 6, lane = tid & 63;
    const int l31  = lane & 31, hi = lane >> 5;
    const int nt   = wave;                       // each wave owns one 32-wide n-tile
    const int m0   = l31, m1 = 32 + l31;         // two m-tiles -> weight frag reuse x2
    const int g0   = (m0 >> 3) & 3, g1 = (m1 >> 3) & 3;
    _Float16* __restrict__ Ha = &sm.Ha[0][0];
    _Float16* __restrict__ Hb = &sm.Hb[0][0];

    // ---- layer 1: K=16 (bias in k=8 slot), D[n][m]
    {
        hv8 a  = *(const hv8*)(wp + nt * 512 + lane * 8);
        hv8 b0 = *(const hv8*)(&sm.xin[m0][0] + hi * 8);
        hv8 b1 = *(const hv8*)(&sm.xin[m1][0] + hi * 8);
        f32x16 z = {};
        f32x16 acc0 = MFMA32(a, b0, z);
        f32x16 acc1 = MFMA32(a, b1, z);
        #pragma unroll
        for (int q = 0; q < 4; ++q) {
            epi_write(Ha, m0, g0, nt, q, hi, acc0[4*q+0], acc0[4*q+1], acc0[4*q+2], acc0[4*q+3]);
            epi_write(Ha, m1, g1, nt, q, hi, acc1[4*q+0], acc1[4*q+1], acc1[4*q+2], acc1[4*q+3]);
        }
    }
    __syncthreads();

    // ---- layer 2: K=256 + bias chunk (ks=16 reads persistent [1,0..] pad col)
    {
        const _Float16* __restrict__ w2 = wp + W2P_OFF + nt * (17 * 512);
        f32x16 acc0 = {}, acc1 = {};
        #pragma unroll 4
        for (int ks = 0; ks < 16; ++ks) {
            hv8 a = *(const hv8*)(w2 + ks * 512 + lane * 8);
            int c = 2 * ks + hi;
            hv8 b0 = *(const hv8*)(Ha + m0 * HPITCH + ((c ^ g0) << 3));
            hv8 b1 = *(const hv8*)(Ha + m1 * HPITCH + ((c ^ g1) << 3));
            acc0 = MFMA32(a, b0, acc0);
            acc1 = MFMA32(a, b1, acc1);
        }
        {   // bias chunk: weights zero for k>256, so both hi halves may read cols 256..263
            hv8 a = *(const hv8*)(w2 + 16 * 512 + lane * 8);
            hv8 b0 = *(const hv8*)(Ha + m0 * HPITCH + 256);
            hv8 b1 = *(const hv8*)(Ha + m1 * HPITCH + 256);
            acc0 = MFMA32(a, b0, acc0);
            acc1 = MFMA32(a, b1, acc1);
        }
        #pragma unroll
        for (int q = 0; q < 4; ++q) {
            epi_write(Hb, m0, g0, nt, q, hi, acc0[4*q+0], acc0[4*q+1], acc0[4*q+2], acc0[4*q+3]);
            epi_write(Hb, m1, g1, nt, q, hi, acc1[4*q+0], acc1[4*q+1], acc1[4*q+2], acc1[4*q+3]);
        }
    }
    __syncthreads();

    // ---- layer 3: 16x16x32, waves 0..3 (one 16-row m-tile each), K=256
    if (wave < 4) {
        const _Float16* __restrict__ w3 = wp + W3P_OFF;
        const int l15 = lane & 15, q = lane >> 4;
        const int m = wave * 16 + l15;
        const int g = (m >> 3) & 3;
        f32x4 acc = {};
        #pragma unroll
        for (int ks = 0; ks < 8; ++ks) {
            hv8 a = *(const hv8*)(w3 + ks * 512 + lane * 8);
            int c = 4 * ks + q;
            hv8 b = *(const hv8*)(Hb + m * HPITCH + ((c ^ g) << 3));
            acc = __builtin_amdgcn_mfma_f32_16x16x32_f16(a, b, acc, 0, 0, 0);
        }
        if (q < 2) {            // n = q*4 + r, valid n < 8
            float4 bv = *(const float4*)(b3 + q * 4);
            float o0 = acc[0] + bv.x, o1 = acc[1] + bv.y, o2 = acc[2] + bv.z, o3 = acc[3] + bv.w;
            if (IS_S) { o0 = tanhf(o0); o1 = tanhf(o1); o2 = tanhf(o2); o3 = tanhf(o3); }
            *(float4*)&stile[m][q * 4] = make_float4(o0, o1, o2, o3);
        }
    }
    // no trailing barrier: the next writer of Ha/Hb syncs before writing (see caller)
}

__global__ __launch_bounds__(512, 4) void coupling_kernel(
    const float* __restrict__ x, const _Float16* __restrict__ wp,
    const float* __restrict__ s1b3, const float* __restrict__ t1b3,
    const float* __restrict__ s2b3, const float* __restrict__ t2b3,
    float* __restrict__ out)
{
    __shared__ SMEM sm;
    const int tid = threadIdx.x;
    const long row0 = (long)blockIdx.x * M_TILE;

    // xin <- [x2, 1, 0...]; Ha pad cols <- [1, 0x7] (persist for all 4 MLPs)
    #pragma unroll
    for (int e = tid; e < M_TILE * 16; e += 512) {
        int row = e >> 4, c = e & 15;
        float v = (c < 8) ? x[(row0 + row) * 16 + 8 + c] : (c == 8 ? 1.0f : 0.0f);
        sm.xin[row][c] = (_Float16)v;
    }
    {
        int m = tid >> 3, c = tid & 7;
        if (m < M_TILE) sm.Ha[m][256 + c] = (c == 0) ? (_Float16)1.0f : (_Float16)0.0f;
    }
    __syncthreads();

    mlp_forward<true >(wp + 0 * NET_STRIDE, s1b3, sm, sm.s_tile);  // s2 = tanh(.)
    mlp_forward<false>(wp + 1 * NET_STRIDE, t1b3, sm, sm.t_tile);  // t2
    __syncthreads();

    // y1 = x1 * exp(s2) + t2 ; ldet partial ; xin <- y1 (col 8 stays 1.0)
    {
        int row = tid >> 3, c = tid & 7;
        float s = sm.s_tile[row][c];
        float t = sm.t_tile[row][c];
        float x1 = x[(row0 + row) * 16 + c];
        float y = x1 * expf(s) + t;
        out[(row0 + row) * 16 + c] = y;
        sm.xin[row][c] = (_Float16)y;
    }
    if (tid < M_TILE) {
        float a = 0.f;
        #pragma unroll
        for (int c = 0; c < 8; ++c) a += sm.s_tile[tid][c];
        sm.ldet[tid] = a;
    }
    __syncthreads();

    mlp_forward<true >(wp + 2 * NET_STRIDE, s2b3, sm, sm.s_tile);  // s1 = tanh(.)
    mlp_forward<false>(wp + 3 * NET_STRIDE, t2b3, sm, sm.t_tile);  // t1
    __syncthreads();

    // y2 = x2 * exp(s1) + t1 ; log_det
    {
        int row = tid >> 3, c = tid & 7;
        float s = sm.s_tile[row][c];
        float t = sm.t_tile[row][c];
        float x2 = x[(row0 + row) * 16 + 8 + c];
        out[(row0 + row) * 16 + 8 + c] = x2 * expf(s) + t;
    }
    if (tid < M_TILE) {
        float a = sm.ldet[tid];
        #pragma unroll
        for (int c = 0; c < 8; ++c) a += sm.s_tile[tid][c];
        out[(long)BATCHN * 16 + row0 + tid] = a;
    }
}

extern "C" void kernel_launch(void* const* d_in, const int* in_sizes, int n_in,
                              void* d_out, int out_size, void* d_ws, size_t ws_size,
                              hipStream_t stream)
{
    const float* x = (const float*)d_in[0];
    const float* s1w1 = (const float*)d_in[1];  const float* s1b1 = (const float*)d_in[2];
    const float* s1w2 = (const float*)d_in[3];  const float* s1b2 = (const float*)d_in[4];
    const float* s1w3 = (const float*)d_in[5];  const float* s1b3 = (const float*)d_in[6];
    const float* t1w1 = (const float*)d_in[7];  const float* t1b1 = (const float*)d_in[8];
    const float* t1w2 = (const float*)d_in[9];  const float* t1b2 = (const float*)d_in[10];
    const float* t1w3 = (const float*)d_in[11]; const float* t1b3 = (const float*)d_in[12];
    const float* s2w1 = (const float*)d_in[13]; const float* s2b1 = (const float*)d_in[14];
    const float* s2w2 = (const float*)d_in[15]; const float* s2b2 = (const float*)d_in[16];
    const float* s2w3 = (const float*)d_in[17]; const float* s2b3 = (const float*)d_in[18];
    const float* t2w1 = (const float*)d_in[19]; const float* t2b1 = (const float*)d_in[20];
    const float* t2w2 = (const float*)d_in[21]; const float* t2b2 = (const float*)d_in[22];
    const float* t2w3 = (const float*)d_in[23]; const float* t2b3 = (const float*)d_in[24];

    _Float16* wp = (_Float16*)d_ws;   // 622592 B used; repacked every launch

    pack_weights<<<(PACK_TOTAL + 255) / 256, 256, 0, stream>>>(
        s1w1, s1b1, s1w2, s1b2, s1w3,
        t1w1, t1b1, t1w2, t1b2, t1w3,
        s2w1, s2b1, s2w2, s2b2, s2w3,
        t2w1, t2b1, t2w2, t2b2, t2w3, wp);

    coupling_kernel<<<BATCHN / M_TILE, 512, 0, stream>>>(
        x, wp, s1b3, t1b3, s2b3, t2b3, (float*)d_out);
}